// Round 1
// baseline (259.520 us; speedup 1.0000x reference)
//
#include <hip/hip_runtime.h>
#include <stdint.h>

// ---------------------------------------------------------------------------
// Equivariant conv = self-connection (folded into center tap) + sparse-tap
// implicit-GEMM bf16 MFMA conv.
// R6: 32x32x16 MFMA with 4x2 acc tiles per wave (128 pos x 64 och) to cut
// LDS read traffic per FLOP from 1/32 to 1/42.7 B/FLOP (B-frag traffic
// halved) and lift the MFMA ceiling 2176->2495 TF. Block = 512 positions
// (8z x 8y x 8x) x 64 och, 4 waves, grid 250 (1 block/CU). Halo double-
// buffered (staging spread across prev chunk's steps); B double-buffered.
// ---------------------------------------------------------------------------

#define NT_REAL 179   // taps with d^2 <= 12 (radial shells vanish beyond r=3.5)
#define NT_PAD  180
#define NPAIR   90    // 2 taps per MFMA k-step (K=16 = 2 taps x 8 ich)

#define XCH  1557376              // shorts per chunk region: 2*46*46*46*8
#define XCHB ((size_t)XCH * 2)    // bytes per chunk region

#define HBYTES 50176              // halo: 14z x 14y x 16x-slots x 16B
#define SEGB   12288              // B segment: 6 pairs x 2048B
#define NSEG   15                 // 15 segments x 6 pairs = 90 pairs

typedef short s16x8 __attribute__((ext_vector_type(8)));
typedef float f32x4 __attribute__((ext_vector_type(4)));
typedef float f32x16 __attribute__((ext_vector_type(16)));

struct Taps {
  int n;
  short dl16[NT_PAD];                       // (dz*14+dy)*16 + dx (halo slot offset)
  unsigned char dz[NT_PAD], dy[NT_PAD], dx[NT_PAD];
};
constexpr Taps mk_taps() {
  Taps t{};
  t.n = 0;
  for (int a = 0; a < 7; ++a)
    for (int b = 0; b < 7; ++b)
      for (int c = 0; c < 7; ++c) {
        int d2 = (a-3)*(a-3) + (b-3)*(b-3) + (c-3)*(c-3);
        if (d2 <= 12) {
          t.dz[t.n] = (unsigned char)a; t.dy[t.n] = (unsigned char)b;
          t.dx[t.n] = (unsigned char)c;
          t.dl16[t.n] = (short)((a*14 + b)*16 + c);
          ++t.n;
        }
      }
  for (int i = t.n; i < NT_PAD; ++i) {      // pad tap: zero weights, valid addr
    t.dz[i] = 3; t.dy[i] = 3; t.dx[i] = 3; t.dl16[i] = t.dl16[0];
  }
  return t;
}
__device__ constexpr Taps TAPS = mk_taps();
static_assert(mk_taps().n == NT_REAL, "tap count");

// 2 tap offsets per pair packed into one u32 (uniform -> s_load)
struct DL2 { unsigned int v[NPAIR]; };
constexpr DL2 mk_dl2() {
  DL2 d{};
  Taps t = mk_taps();
  for (int p = 0; p < NPAIR; ++p)
    d.v[p] = (unsigned int)(unsigned short)t.dl16[2*p]
           | ((unsigned int)(unsigned short)t.dl16[2*p + 1] << 16);
  return d;
}
__device__ constexpr DL2 DL2V = mk_dl2();

static __device__ inline unsigned short f2bf(float f) {   // RNE fp32->bf16
  unsigned int u = __float_as_uint(f);
  unsigned int r = u + 0x7FFFu + ((u >> 16) & 1u);
  return (unsigned short)(r >> 16);
}

__device__ __forceinline__ void gl_lds16(const void* g, void* s) {
  // async 16B/lane global->LDS; LDS dest = wave-uniform base + lane*16
  __builtin_amdgcn_global_load_lds(
      (const __attribute__((address_space(1))) void*)g,
      (__attribute__((address_space(3))) void*)s, 16, 0, 0);
}

// ---------------------------------------------------------------------------
// prep: blocks [0,800) = pad/convert x -> Xp interior (borders pre-zeroed by
// hipMemsetAsync); blocks [800,980) = build Bwp.
//   Xp chunk-major: [chunk8][b2][46][46][46][8ch] bf16 (16 B per pos/chunk).
//   Bwp[chunk8][pair90][og2][hi2][col32][j8]: MFMA (32x32x16) k = hi*8+j <->
//   (tap=pair*2+hi, ich=chunk*8+j); och = og*32+col. Lane (hi,col) B fragment
//   at byte (hi*32+col)*16 = lane*16 within the 1024B og-line.
// ---------------------------------------------------------------------------
__global__ void prep(const float* __restrict__ x, const float* __restrict__ scw0,
                     const float* __restrict__ scw1, const float* __restrict__ tpw,
                     unsigned short* __restrict__ Xp, unsigned short* __restrict__ Bwp) {
  __shared__ float buf[160 * 65];           // pad: transpose buf / build: wsm alias
  int tid = threadIdx.x;

  if (blockIdx.x < 800) {                   // ---- pad/convert (coalesced) ----
    int blk = blockIdx.x;                   // (b*40 + iz)*10 + ystrip
    int ys = blk % 10; int t2 = blk / 10; int iz = t2 % 40; int b = t2 / 40;
    int y0 = ys * 4;
    const float* src = x + (size_t)b * 4096000 + (size_t)iz * 1600 + (size_t)y0 * 40;
    for (int e = tid; e < 64 * 160; e += 256) {
      int ch = e / 160, i = e - ch * 160;
      buf[i * 65 + ch] = src[(size_t)ch * 64000 + i];   // contiguous per ch
    }
    __syncthreads();
    for (int f = tid; f < 160 * 8; f += 256) {
      int i = f >> 3, g = f & 7;
      int yy = i / 40, xx = i - yy * 40;
      s16x8 v;
      #pragma unroll
      for (int j = 0; j < 8; ++j) v[j] = (short)f2bf(buf[i * 65 + g * 8 + j]);
      size_t pos = ((size_t)((b * 46 + iz + 3) * 46 + (y0 + yy + 3)) * 46 + (xx + 3));
      *reinterpret_cast<s16x8*>(Xp + (size_t)g * XCH + pos * 8) = v;
    }
    return;
  }

  // ---- build weights ----
  int t = blockIdx.x - 800;                 // 0..179
  float (*wsm)[16][16] = reinterpret_cast<float (*)[16][16]>(buf);

  int dz = TAPS.dz[t], dy = TAPS.dy[t], dx = TAPS.dx[t];
  float fz = dz - 3.0f, fy = dy - 3.0f, fx = dx - 3.0f;
  float d2 = fz*fz + fy*fy + fx*fx;
  float r = sqrtf(d2);

  const float step = 3.5f / 9.0f;
  const float Cc = 1.14136f * 7.38905609893065f;   // 1.14136 * e^2
  float emb[8];
  for (int bb = 0; bb < 8; ++bb) {
    float diff = (r - step * (bb + 1)) / step;
    float t1 = diff + 1.0f, t2 = 1.0f - diff;
    float u1 = (t1 > 0.0f) ? expf(-1.0f / t1) : 0.0f;
    float u2 = (t2 > 0.0f) ? expf(-1.0f / t2) : 0.0f;
    emb[bb] = Cc * u1 * u2;
  }

  int u = tid >> 4, o = tid & 15;
  for (int p = 0; p < 5; ++p) {
    float acc = 0.0f;
    int nidx = (p * 16 + u) * 16 + o;
    for (int bb = 0; bb < 8; ++bb) acc += emb[bb] * tpw[bb * 1280 + nidx];
    wsm[p][u][o] = acc * (1.0f / 343.0f);
  }
  __syncthreads();

  float invr = (d2 > 0.0f) ? (1.7320508075688772f / r) : 0.0f;  // sqrt(3)/r
  float sh[3] = { fz * invr, fy * invr, fx * invr };

  bool center = (dz == 3 && dy == 3 && dx == 3);
  bool padt = (t >= NT_REAL);
  const float c1 = 0.17677669529663687f;   // sqrt(1/32)
  const float c2 = 0.10206207261596575f;   // c1/sqrt(3)
  const float c3 = 0.14433756729740643f;   // 0.25/sqrt(3)
  const float c4 = 0.14433756729740643f;
  const float c5 = 0.10206207261596575f;   // 0.25/sqrt(6)
  const float inv = 0.25f;                 // 1/sqrt(MUL)

  for (int e = tid; e < 4096; e += 256) {
    int ich = e & 63, och = e >> 6;
    float v = 0.0f;
    if (!padt) {
      if (och < 16) {
        if (ich < 16) {                               // scalar->scalar
          v = c1 * wsm[0][ich][och];
          if (center) v += inv * scw0[ich * 16 + och];
        } else {                                      // vector->scalar
          int qq = ich - 16; int uu = qq / 3, ii = qq % 3;
          v = c2 * sh[ii] * wsm[1][uu][och];
        }
      } else {
        int qo = och - 16; int oo = qo / 3, kk = qo % 3;
        if (ich < 16) {                               // scalar->vector
          v = c3 * sh[kk] * wsm[2][ich][oo];
        } else {                                      // vector->vector
          int qi = ich - 16; int uu = qi / 3, ii = qi % 3;
          if (ii == kk) {
            v = c4 * wsm[3][uu][oo];
            if (center) v += inv * scw1[uu * 16 + oo];
          } else {
            int jj = 3 - ii - kk;
            float sgn = (((kk - ii + 3) % 3) == 2) ? 1.0f : -1.0f;
            v = c5 * sgn * sh[jj] * wsm[4][uu][oo];
          }
        }
      }
    }
    int chunk = ich >> 3, j = ich & 7;
    int pair = t >> 1, hi = t & 1;
    int og = och >> 5, col = och & 31;
    size_t idx = ((((size_t)chunk * NPAIR + pair) * 2 + og) * 2 + hi) * 256
               + (size_t)col * 8 + j;
    Bwp[idx] = f2bf(v);
  }
}

// ---------------------------------------------------------------------------
// conv3d: implicit-GEMM, 32x32x16 bf16 MFMA. Block = 256 thr (4 waves),
// tile = 512 output positions (8z x 8y x 8x) x 64 och; grid 256 (6 dummies)
// -> 1 block/CU, 250 live blocks. Wave w owns z-planes {2w, 2w+1}: 4 A-frags
// (zz x y-half, 32 pos each) x 2 B-frags (32 och) -> acc[4][2] of f32x16
// (128 VGPRs). Per K=16 pair-step: 6 b128 reads feed 8 MFMAs (42.7 FLOP/B
// vs 32 for the 16x16 4x4 tiling -> B-side LDS traffic halved).
// 120 steps (8 ich-chunks x 15 segments of 6 tap-pairs). Halo (14x14x16
// slots x16B = 50176B) double-buffered, staged 1 line/wave/step during the
// previous chunk; B segments (12288B) double-buffered. LDS 124928B.
// ---------------------------------------------------------------------------
__global__ __launch_bounds__(256, 1) void conv3d(
    const unsigned short* __restrict__ Xp,   // [8][2][46][46][46][8] bf16
    const unsigned short* __restrict__ Bwp,  // [8][90][2][2][32][8] bf16
    float* __restrict__ out) {               // [2][64][40][40][40] fp32
  __shared__ __align__(16) unsigned char smem[2 * HBYTES + 2 * SEGB];
  unsigned char* BB = smem + 2 * HBYTES;     // 2 x 12288

  int blk = blockIdx.x;                      // 256, 6 dummies
  int p = ((blk & 7) << 5) | (blk >> 3);     // XCD-contiguous tile ranges
  if (p >= 250) return;
  int b = p / 125; int rem = p - b * 125;
  int tz = rem / 25, ty = (rem / 5) % 5, tx = rem % 5;

  int tid = threadIdx.x;
  int lane = tid & 63;
  int w = tid >> 6;                          // wave 0..3 -> z-planes {2w,2w+1}
  int hi = lane >> 5, r32 = lane & 31;
  int hs = hi << 4;                          // shift for dl extraction

  // dense per-chunk halo source base (16 B per position)
  size_t hbase = (size_t)(((b * 46 + tz * 8) * 46 + ty * 8) * 46 + tx * 8) * 16;

  // A fragment base slot: z = 2w (z stride 14*16=224 slots), y_rel = r32>>3,
  // x = r32&7. Frag offsets: +aq*64 slots (4 y-rows), +zz*224 slots (1 z).
  int abase = w * 448 + ((r32 >> 3) << 4) + (r32 & 7);

  f32x16 acc[4][2];                          // [zz*2+aq][og]
  #pragma unroll
  for (int f = 0; f < 4; ++f)
    #pragma unroll
    for (int og = 0; og < 2; ++og)
      #pragma unroll
      for (int e = 0; e < 16; ++e) acc[f][og][e] = 0.0f;

  auto stageB = [&](int c, int seg, unsigned char* dst) {
    const unsigned char* bg = (const unsigned char*)Bwp
        + ((size_t)c * NPAIR + seg * 6) * 2048;        // 6 pairs x 2048 B
    for (int k = w; k < 12; k += 4)
      gl_lds16(bg + (k << 10) + lane * 16, dst + (k << 10));
  };
  auto stageHLine = [&](int c, int k, unsigned char* dst) {  // one 1024B line
    const unsigned char* xc = (const unsigned char*)Xp + (size_t)c * XCHB + hbase;
    int sl = (k << 6) + lane;
    int hx = sl & 15; hx = hx > 13 ? 13 : hx;          // phantom x-slots clamp
    int r = sl >> 4;                                   // hz*14+hy, < 196
    int hz = (r * 2341) >> 15;                         // r/14
    int hy = r - hz * 14;
    gl_lds16(xc + ((size_t)((hz * 46 + hy) * 46 + hx)) * 16, dst + (k << 10));
  };

  // prologue: full halo chunk 0 (49 lines) + B seg 0
  for (int k = w; k < 49; k += 4) stageHLine(0, k, smem);
  stageB(0, 0, BB);
  __syncthreads();

  int t = 0;
  for (int c = 0; c < 8; ++c) {
    unsigned char* XH  = smem + (c & 1) * HBYTES;
    unsigned char* XHn = smem + ((c + 1) & 1) * HBYTES;
    for (int s = 0; s < NSEG; ++s, ++t) {
      if (t + 1 < 120) {                               // next B seg in flight
        int cn = (s == NSEG - 1) ? c + 1 : c;
        int sn = (s == NSEG - 1) ? 0 : s + 1;
        stageB(cn, sn, BB + ((t + 1) & 1) * SEGB);
      }
      if (c + 1 < 8) {                                 // spread next halo
        int L = s * 4 + w;                             // 60 slots >= 49 lines
        if (L < 49) stageHLine(c + 1, L, XHn);
      }
      const unsigned char* BSc = BB + (t & 1) * SEGB + (size_t)lane * 16;
      #pragma unroll
      for (int pp = 0; pp < 6; ++pp) {
        unsigned int dlv = DL2V.v[s * 6 + pp];         // uniform -> s_load
        int dl = (int)((dlv >> hs) & 0xFFFFu);         // tap offset for k-half
        const unsigned char* ab = XH + ((size_t)(abase + dl) << 4);
        s16x8 a00 = *(const s16x8*)(ab);               // zz0, y-rows 0..3
        s16x8 a01 = *(const s16x8*)(ab + 1024);        // zz0, y-rows 4..7
        s16x8 a10 = *(const s16x8*)(ab + 3584);        // zz1, y-rows 0..3
        s16x8 a11 = *(const s16x8*)(ab + 4608);        // zz1, y-rows 4..7
        const unsigned char* bp = BSc + (pp << 11);
        s16x8 b0 = *(const s16x8*)(bp);                // och 0..31
        s16x8 b1 = *(const s16x8*)(bp + 1024);         // och 32..63
        acc[0][0] = __builtin_amdgcn_mfma_f32_32x32x16_bf16(a00, b0, acc[0][0], 0, 0, 0);
        acc[0][1] = __builtin_amdgcn_mfma_f32_32x32x16_bf16(a00, b1, acc[0][1], 0, 0, 0);
        acc[1][0] = __builtin_amdgcn_mfma_f32_32x32x16_bf16(a01, b0, acc[1][0], 0, 0, 0);
        acc[1][1] = __builtin_amdgcn_mfma_f32_32x32x16_bf16(a01, b1, acc[1][1], 0, 0, 0);
        acc[2][0] = __builtin_amdgcn_mfma_f32_32x32x16_bf16(a10, b0, acc[2][0], 0, 0, 0);
        acc[2][1] = __builtin_amdgcn_mfma_f32_32x32x16_bf16(a10, b1, acc[2][1], 0, 0, 0);
        acc[3][0] = __builtin_amdgcn_mfma_f32_32x32x16_bf16(a11, b0, acc[3][0], 0, 0, 0);
        acc[3][1] = __builtin_amdgcn_mfma_f32_32x32x16_bf16(a11, b1, acc[3][1], 0, 0, 0);
      }
      __syncthreads();    // drains next B stage + halo lines, gates reuse
    }
  }

  // ---- epilogue: 32x32 D map: col=lane&31 (och), row=(reg&3)+8*(reg>>2)+4*hi
  // row -> y_sub = reg>>2, x = (reg&3)+4*hi ; frag f=(zz,aq): z=2w+zz, y+=aq*4
  int col = lane & 31;
  #pragma unroll
  for (int og = 0; og < 2; ++og) {
    #pragma unroll
    for (int f = 0; f < 4; ++f) {
      int zz = f >> 1, aq = f & 1;
      size_t cb = (size_t)(b * 64 + og * 32 + col) * 64000
                + (size_t)(tz * 8 + 2 * w + zz) * 1600
                + (size_t)(tx * 8 + hi * 4);
      #pragma unroll
      for (int ys = 0; ys < 4; ++ys) {
        float* dst = out + cb + (size_t)(ty * 8 + aq * 4 + ys) * 40;
        f32x4 v = { acc[f][og][ys * 4 + 0], acc[f][og][ys * 4 + 1],
                    acc[f][og][ys * 4 + 2], acc[f][og][ys * 4 + 3] };
        *reinterpret_cast<f32x4*>(dst) = v;
      }
    }
  }
}

// ---------------------------------------------------------------------------
extern "C" void kernel_launch(void* const* d_in, const int* in_sizes, int n_in,
                              void* d_out, int out_size, void* d_ws, size_t ws_size,
                              hipStream_t stream) {
  const float* x    = (const float*)d_in[0];  // [2,64,40,40,40]
  const float* scw0 = (const float*)d_in[1];  // [16,16]
  const float* scw1 = (const float*)d_in[2];  // [16,16]
  const float* tpw  = (const float*)d_in[3];  // [8,1280]
  float* out = (float*)d_out;

  unsigned short* Xp  = (unsigned short*)d_ws;                 // 24,918,016 B
  unsigned short* Bwp = Xp + (size_t)8 * XCH;                  // 1,474,560 B

  hipMemsetAsync(Xp, 0, (size_t)8 * XCH * 2, stream);
  prep<<<800 + NT_PAD, 256, 0, stream>>>(x, scw0, scw1, tpw, Xp, Bwp);
  conv3d<<<256, 256, 0, stream>>>(Xp, Bwp, out);
}